// Round 11
// baseline (46.746 us; speedup 1.0000x reference)
//
#include <hip/hip_runtime.h>
#include <hip/hip_bf16.h>

#define S_ 1024
#define E_ 768
#define H_ 12

typedef __bf16  bf16x8 __attribute__((ext_vector_type(8)));
typedef float   f32x4  __attribute__((ext_vector_type(4)));
typedef unsigned short u16x8 __attribute__((ext_vector_type(8)));
typedef unsigned short u16x4 __attribute__((ext_vector_type(4)));

__device__ __forceinline__ unsigned short f2bf(float f) {
    union { float f; unsigned u; } a; a.f = f;
    unsigned u = a.u;
    u += 0x7FFFu + ((u >> 16) & 1u);   // RNE
    return (unsigned short)(u >> 16);
}

__device__ __forceinline__ u16x8 pack8(float4 a, float4 b) {
    u16x8 o;
    o[0] = f2bf(a.x); o[1] = f2bf(a.y); o[2] = f2bf(a.z); o[3] = f2bf(a.w);
    o[4] = f2bf(b.x); o[5] = f2bf(b.y); o[6] = f2bf(b.z); o[7] = f2bf(b.w);
    return o;
}

// LDS tile: 64 rows x 64 bf16 (128B/row, 8x16B chunks).
// LDS linear; swizzle lives in the GLOBAL source offset (g = cb ^ (row&7)); read XORs back.
__device__ __forceinline__ bf16x8 ld_frag(const char* lbase, int row, int kk, int lane) {
    int cbyte = (kk * 64 + ((lane >> 4) * 16)) ^ ((row & 7) << 4);
    return *(const bf16x8*)(lbase + row * 128 + cbyte);
}

// -------- prep (W only): Wq*(lin_w/sqrt8)->bf16, Wk->bf16, bq scaled --------
__global__ __launch_bounds__(256) void prep_w_kernel(
    const float* __restrict__ Wq, const float* __restrict__ Wk,
    const float* __restrict__ bq, const float* __restrict__ lin_w,
    unsigned short* __restrict__ Wqbf, unsigned short* __restrict__ Wkbf,
    float* __restrict__ bqs)
{
    const float invs = 0.35355339059327373f; // 1/sqrt(8)
    int u = blockIdx.x * 256 + threadIdx.x;  // float4 index, 0..294911
    if (u < 147456) {                        // Wq (scaled)
        int i = u * 4;
        int n = i / E_;
        float w = lin_w[(n & 63) >> 3] * invs;
        float4 v = *(const float4*)(Wq + i);
        *(ushort4*)(Wqbf + i) = make_ushort4(f2bf(v.x * w), f2bf(v.y * w), f2bf(v.z * w), f2bf(v.w * w));
        if (u < E_) bqs[u] = bq[u] * (lin_w[(u & 63) >> 3] * invs);
    } else {                                 // Wk
        int i = (u - 147456) * 4;
        float4 v = *(const float4*)(Wk + i);
        *(ushort4*)(Wkbf + i) = make_ushort4(f2bf(v.x), f2bf(v.y), f2bf(v.z), f2bf(v.w));
    }
}

// ---------------- proj: P[m,n] = sum_k X[m,k]*Wbf[n,k] + bias[n], bf16 out ----------------
// X read fp32 DIRECTLY (reg-stage: load->cvt->ds_write, T14 issue-early/write-late, 2-buf ring);
// W bf16 via global_load_lds ring-3. Counted vmcnt(8) steady state; raw s_barrier. XCD swizzle.
__global__ __launch_bounds__(256) void proj_kernel(
    const float* __restrict__ q_in, const float* __restrict__ k_in,
    const unsigned short* __restrict__ Wqbf, const unsigned short* __restrict__ Wkbf,
    const float* __restrict__ bqs, const float* __restrict__ bk,
    unsigned short* __restrict__ qs, unsigned short* __restrict__ kp)
{
    __shared__ char lds[2 * 8192 + 3 * 8192];   // X bufs @0,8192 ; W bufs @16384+buf*8192

    int lid = blockIdx.x;
    int swz = (lid & 7) * 96 + (lid >> 3);   // XCD-chunked (768 % 8 == 0, bijective)
    int z  = swz / 384;
    int rem = swz - z * 384;
    int ty = rem / 12, tx = rem - ty * 12;
    int tm = ty * 64, tn = tx * 64;

    const float* X          = z ? k_in : q_in;
    const unsigned short* W = z ? Wkbf : Wqbf;
    const float* bias       = z ? bk   : bqs;
    unsigned short* P       = z ? kp   : qs;

    int tid = threadIdx.x, lane = tid & 63, wid = tid >> 6;
    int wn = wid >> 1, wm = wid & 1;

    int c0 = tid,        r0 = c0 >> 3, g0 = ((c0 & 7) ^ (r0 & 7)) * 8;
    int c1 = 256 + tid,  r1 = c1 >> 3, g1 = ((c1 & 7) ^ (r1 & 7)) * 8;

    const float* Xg          = X + (size_t)tm * E_;
    const unsigned short* Wg = W + (size_t)tn * E_;

#define GLL(src, dst) __builtin_amdgcn_global_load_lds( \
        (const __attribute__((address_space(1))) void*)(src), \
        (__attribute__((address_space(3))) void*)(dst), 16, 0, 0)
#define GLLW(kb, buf) { \
    char* wb = lds + 16384 + (buf) * 8192; \
    GLL(Wg + (size_t)r0 * E_ + (kb) + g0, wb + c0 * 16); \
    GLL(Wg + (size_t)r1 * E_ + (kb) + g1, wb + c1 * 16); }
#define LOADX(kb) { \
    const float* xs0 = Xg + r0 * E_ + (kb) + g0; xv0 = *(const float4*)xs0; xv1 = *(const float4*)(xs0 + 4); \
    const float* xs1 = Xg + r1 * E_ + (kb) + g1; xv2 = *(const float4*)xs1; xv3 = *(const float4*)(xs1 + 4); }
#define WRITEX(buf) { \
    char* xb = lds + (buf) * 8192; \
    *(u16x8*)(xb + c0 * 16) = pack8(xv0, xv1); \
    *(u16x8*)(xb + c1 * 16) = pack8(xv2, xv3); }

    float4 xv0, xv1, xv2, xv3;

    f32x4 acc[2][2];
#pragma unroll
    for (int nj = 0; nj < 2; ++nj) {
        int n0 = tn + wn * 32 + nj * 16 + ((lane >> 4) << 2);
        float4 b4 = *(const float4*)(bias + n0);
#pragma unroll
        for (int mi = 0; mi < 2; ++mi)
            acc[nj][mi] = f32x4{b4.x, b4.y, b4.z, b4.w};
    }

#define COMPSTEP(xbuf, wbuf) { \
    const char* Xc = lds + (xbuf) * 8192; \
    const char* Wc = lds + 16384 + (wbuf) * 8192; \
    _Pragma("unroll") \
    for (int kk = 0; kk < 2; ++kk) { \
        bf16x8 a0 = ld_frag(Wc, wn * 32 + (lane & 15), kk, lane); \
        bf16x8 a1 = ld_frag(Wc, wn * 32 + 16 + (lane & 15), kk, lane); \
        bf16x8 b0 = ld_frag(Xc, wm * 32 + (lane & 15), kk, lane); \
        bf16x8 b1 = ld_frag(Xc, wm * 32 + 16 + (lane & 15), kk, lane); \
        acc[0][0] = __builtin_amdgcn_mfma_f32_16x16x32_bf16(a0, b0, acc[0][0], 0, 0, 0); \
        acc[0][1] = __builtin_amdgcn_mfma_f32_16x16x32_bf16(a0, b1, acc[0][1], 0, 0, 0); \
        acc[1][0] = __builtin_amdgcn_mfma_f32_16x16x32_bf16(a1, b0, acc[1][0], 0, 0, 0); \
        acc[1][1] = __builtin_amdgcn_mfma_f32_16x16x32_bf16(a1, b1, acc[1][1], 0, 0, 0); \
    } }

    // ---- prologue: W0,W1 gll'd; X0 staged ----
    GLLW(0, 0);
    LOADX(0);
    GLLW(64, 1);
    WRITEX(0);                                          // compiler waits xv (vmcnt(2): W1 in flight)
    asm volatile("s_waitcnt lgkmcnt(0)" ::: "memory");
    __builtin_amdgcn_s_barrier();
    __builtin_amdgcn_sched_barrier(0);

    int xc = 0, wc = 0, wn2 = 2;
    for (int t = 0; t < 10; ++t) {
        LOADX((t + 1) * 64);                            // X(t+1) -> regs (issue-early)
        GLLW((t + 2) * 64, wn2);                        // W(t+2) -> ring
        __builtin_amdgcn_sched_barrier(0);
        asm volatile("s_waitcnt vmcnt(8)" ::: "memory"); // W(t) landed; X(t+1)4+W(t+1)2+W(t+2)2 in flight
        __builtin_amdgcn_sched_barrier(0);
        COMPSTEP(xc, wc);
        WRITEX(xc ^ 1);                                 // write-late (compiler waits xv: vmcnt(2))
        asm volatile("s_waitcnt lgkmcnt(0)" ::: "memory");
        __builtin_amdgcn_s_barrier();
        __builtin_amdgcn_sched_barrier(0);
        xc ^= 1;
        wc = wc == 2 ? 0 : wc + 1;
        wn2 = wn2 == 2 ? 0 : wn2 + 1;
    }
    // ---- tail: tiles 10, 11 ----
    LOADX(11 * 64);
    __builtin_amdgcn_sched_barrier(0);
    asm volatile("s_waitcnt vmcnt(6)" ::: "memory");    // W(10) landed; X(11)4+W(11)2 in flight
    __builtin_amdgcn_sched_barrier(0);
    COMPSTEP(0, 1);                                     // t=10: xbuf 0, wbuf 1
    WRITEX(1);
    asm volatile("s_waitcnt lgkmcnt(0)" ::: "memory");
    __builtin_amdgcn_s_barrier();
    __builtin_amdgcn_sched_barrier(0);
    asm volatile("s_waitcnt vmcnt(0)" ::: "memory");    // W(11)
    __builtin_amdgcn_sched_barrier(0);
    COMPSTEP(1, 2);                                     // t=11: xbuf 1, wbuf 2

#pragma unroll
    for (int nj = 0; nj < 2; ++nj)
#pragma unroll
        for (int mi = 0; mi < 2; ++mi) {
            int n0 = tn + wn * 32 + nj * 16 + ((lane >> 4) << 2);
            int m  = tm + wm * 32 + mi * 16 + (lane & 15);
            u16x4 pk;
            pk[0] = f2bf(acc[nj][mi][0]); pk[1] = f2bf(acc[nj][mi][1]);
            pk[2] = f2bf(acc[nj][mi][2]); pk[3] = f2bf(acc[nj][mi][3]);
            *(u16x4*)(P + (size_t)m * E_ + n0) = pk;
        }
#undef GLL
#undef GLLW
#undef LOADX
#undef WRITEX
#undef COMPSTEP
}

// ---------------- scores: per (b,h): out[i,j] = qs_i . kp_j + lin_b, fp32 out ----------------
// LDS-FREE, barrier-free: waves partition j (wj) and i (wi); no K row is shared within a block,
// so K fragments load straight to registers (same addressing as Q). Cross-block reuse via L2
// (XCD-chunked swizzle). No sync points -> no vmcnt drains; TLP hides all latency.
__global__ __launch_bounds__(256) void scores_kernel(
    const unsigned short* __restrict__ qs, const unsigned short* __restrict__ kp,
    const float* __restrict__ lin_b, float* __restrict__ out)
{
    int lid = blockIdx.x;
    int swz = (lid & 7) * 96 + (lid >> 3);   // 768 % 8 == 0, bijective
    int z   = swz >> 5;                      // 32 blocks per head
    int rem = swz & 31;
    int iy  = rem >> 2, jx = rem & 3;
    int b = z / H_, h = z - b * H_;

    int tid = threadIdx.x, lane = tid & 63, wid = tid >> 6;
    int wj = wid >> 1, wi = wid & 1;
    int ti = iy * 128, tj = jx * 256;

    const unsigned short* Qg = qs + (size_t)(b * S_) * E_ + h * 64;
    const unsigned short* Kg = kp + (size_t)(b * S_) * E_ + h * 64;

    bf16x8 qf[2][4];
    int qrow = ti + wi * 64 + (lane & 15);
#pragma unroll
    for (int ni = 0; ni < 4; ++ni)
#pragma unroll
        for (int kk = 0; kk < 2; ++kk)
            qf[kk][ni] = *(const bf16x8*)(Qg + (size_t)(qrow + ni * 16) * E_ + kk * 32 + ((lane >> 4) * 8));

    float lb0 = lin_b[0];
    float* O = out + ((size_t)z << 20);

#pragma unroll
    for (int sub = 0; sub < 2; ++sub) {
        // K fragments direct to registers (A-operand; same lane mapping as B)
        bf16x8 kf[2][4];
        int krow = tj + sub * 128 + wj * 64 + (lane & 15);
#pragma unroll
        for (int mj = 0; mj < 4; ++mj)
#pragma unroll
            for (int kk = 0; kk < 2; ++kk)
                kf[kk][mj] = *(const bf16x8*)(Kg + (size_t)(krow + mj * 16) * E_ + kk * 32 + ((lane >> 4) * 8));

        f32x4 acc[4][4];
#pragma unroll
        for (int mj = 0; mj < 4; ++mj)
#pragma unroll
            for (int ni = 0; ni < 4; ++ni) acc[mj][ni] = f32x4{lb0, lb0, lb0, lb0};

#pragma unroll
        for (int kk = 0; kk < 2; ++kk)
#pragma unroll
            for (int mj = 0; mj < 4; ++mj)
#pragma unroll
                for (int ni = 0; ni < 4; ++ni)
                    acc[mj][ni] = __builtin_amdgcn_mfma_f32_16x16x32_bf16(kf[kk][mj], qf[kk][ni], acc[mj][ni], 0, 0, 0);

#pragma unroll
        for (int mj = 0; mj < 4; ++mj)
#pragma unroll
            for (int ni = 0; ni < 4; ++ni) {
                int i  = ti + wi * 64 + ni * 16 + (lane & 15);
                int j0 = tj + sub * 128 + wj * 64 + mj * 16 + ((lane >> 4) << 2);
                *(f32x4*)(O + (size_t)i * S_ + j0) = acc[mj][ni];
            }
    }
}

extern "C" void kernel_launch(void* const* d_in, const int* in_sizes, int n_in,
                              void* d_out, int out_size, void* d_ws, size_t ws_size,
                              hipStream_t stream)
{
    const float* k_in  = (const float*)d_in[0];
    const float* q_in  = (const float*)d_in[1];
    const float* Wq_w  = (const float*)d_in[2];
    const float* Wq_b  = (const float*)d_in[3];
    const float* Wk_w  = (const float*)d_in[4];
    const float* Wk_b  = (const float*)d_in[5];
    const float* lin_w = (const float*)d_in[6];
    const float* lin_b = (const float*)d_in[7];
    float* out = (float*)d_out;

    char* ws = (char*)d_ws;
    unsigned short* Wqbf = (unsigned short*)(ws + 0);
    unsigned short* Wkbf = (unsigned short*)(ws + 1179648);
    float*          bqs  = (float*)        (ws + 2359296);
    unsigned short* qsb  = (unsigned short*)(ws + 2362368);
    unsigned short* kpb  = (unsigned short*)(ws + 5508096);

    // 1) prep (W only): Wq scaled->bf16, Wk->bf16, bqs
    prep_w_kernel<<<dim3(1152), dim3(256), 0, stream>>>(Wq_w, Wk_w, Wq_b, lin_w, Wqbf, Wkbf, bqs);
    // 2) projections: X fp32 reg-staged in-kernel (no q/k cast round-trip), W gll ring-3, counted vmcnt
    proj_kernel<<<dim3(768), dim3(256), 0, stream>>>(q_in, k_in, Wqbf, Wkbf, bqs, Wk_b, qsb, kpb);
    // 3) scores: LDS-free, barrier-free, K/Q direct-to-register
    scores_kernel<<<dim3(768), dim3(256), 0, stream>>>(qsb, kpb, lin_b, out);
}

// Round 12
// 42.242 us; speedup vs baseline: 1.1066x; 1.1066x over previous
//
#include <hip/hip_runtime.h>
#include <hip/hip_bf16.h>

#define S_ 1024
#define E_ 768
#define H_ 12

typedef __bf16  bf16x8 __attribute__((ext_vector_type(8)));
typedef float   f32x4  __attribute__((ext_vector_type(4)));
typedef unsigned short u16x4 __attribute__((ext_vector_type(4)));

__device__ __forceinline__ unsigned short f2bf(float f) {
    union { float f; unsigned u; } a; a.f = f;
    unsigned u = a.u;
    u += 0x7FFFu + ((u >> 16) & 1u);   // RNE
    return (unsigned short)(u >> 16);
}

// LDS tile layout: R rows x 64 bf16 (128B/row, 8x16B chunks).
// Physical chunk (row, cb) holds global chunk (row, cb ^ (row&7)).
__device__ __forceinline__ bf16x8 ld_frag(const char* lbase, int row, int kk, int lane) {
    int cbyte = (kk * 64 + ((lane >> 4) * 16)) ^ ((row & 7) << 4);
    return *(const bf16x8*)(lbase + row * 128 + cbyte);
}

// -------- prep: Wq*(lin_w/sqrt8)->bf16, Wk->bf16, bq scaled, q/k->bf16. One 1D launch. --------
__global__ __launch_bounds__(256) void prep_cast_kernel(
    const float* __restrict__ q_in, const float* __restrict__ k_in,
    const float* __restrict__ Wq, const float* __restrict__ Wk,
    const float* __restrict__ bq, const float* __restrict__ lin_w,
    unsigned short* __restrict__ Wqbf, unsigned short* __restrict__ Wkbf,
    unsigned short* __restrict__ qbf, unsigned short* __restrict__ kbf,
    float* __restrict__ bqs)
{
    const float invs = 0.35355339059327373f; // 1/sqrt(8)
    int u = blockIdx.x * 256 + threadIdx.x;  // float4 index
    if (u < 147456) {                        // Wq (scaled)
        int i = u * 4;
        int n = i / E_;
        float w = lin_w[(n & 63) >> 3] * invs;
        float4 v = *(const float4*)(Wq + i);
        *(ushort4*)(Wqbf + i) = make_ushort4(f2bf(v.x * w), f2bf(v.y * w), f2bf(v.z * w), f2bf(v.w * w));
        if (u < E_) bqs[u] = bq[u] * (lin_w[(u & 63) >> 3] * invs);
    } else if (u < 294912) {                 // Wk
        int i = (u - 147456) * 4;
        float4 v = *(const float4*)(Wk + i);
        *(ushort4*)(Wkbf + i) = make_ushort4(f2bf(v.x), f2bf(v.y), f2bf(v.z), f2bf(v.w));
    } else if (u < 688128) {                 // q
        int i = (u - 294912) * 4;
        float4 v = *(const float4*)(q_in + i);
        *(ushort4*)(qbf + i) = make_ushort4(f2bf(v.x), f2bf(v.y), f2bf(v.z), f2bf(v.w));
    } else {                                 // k
        int i = (u - 688128) * 4;
        float4 v = *(const float4*)(k_in + i);
        *(ushort4*)(kbf + i) = make_ushort4(f2bf(v.x), f2bf(v.y), f2bf(v.z), f2bf(v.w));
    }
}

// ---------------- proj: P[m,n] = sum_k X[m,k]*Wbf[n,k] + bias[n], bf16 out ----------------
// R9 structure: ring-3 counted-vmcnt pipeline, all-bf16 global_load_lds, XCD swizzle.
// R12 delta: s_setprio(1) around the MFMA cluster (T5; counted-vmcnt phase structure).
__global__ __launch_bounds__(256) void proj_kernel(
    const unsigned short* __restrict__ qbf, const unsigned short* __restrict__ kbf,
    const unsigned short* __restrict__ Wqbf, const unsigned short* __restrict__ Wkbf,
    const float* __restrict__ bqs, const float* __restrict__ bk,
    unsigned short* __restrict__ qs, unsigned short* __restrict__ kp)
{
    __shared__ char lds[3 * 16384];   // ring of 3 bufs: each {X 8K | W 8K}

    int lid = blockIdx.x;
    int swz = (lid & 7) * 96 + (lid >> 3);   // XCD-chunked (768 % 8 == 0, bijective)
    int z  = swz / 384;
    int rem = swz - z * 384;
    int ty = rem / 12, tx = rem - ty * 12;
    int tm = ty * 64, tn = tx * 64;

    const unsigned short* X = z ? kbf : qbf;
    const unsigned short* W = z ? Wkbf : Wqbf;
    const float* bias       = z ? bk   : bqs;
    unsigned short* P       = z ? kp   : qs;

    int tid = threadIdx.x, lane = tid & 63, wid = tid >> 6;
    int wn = wid >> 1, wm = wid & 1;

    int c0 = tid,        r0 = c0 >> 3, g0 = ((c0 & 7) ^ (r0 & 7)) * 8;
    int c1 = 256 + tid,  r1 = c1 >> 3, g1 = ((c1 & 7) ^ (r1 & 7)) * 8;

    const unsigned short* Xg = X + (size_t)tm * E_;
    const unsigned short* Wg = W + (size_t)tn * E_;

#define GLL(src, dst) __builtin_amdgcn_global_load_lds( \
        (const __attribute__((address_space(1))) void*)(src), \
        (__attribute__((address_space(3))) void*)(dst), 16, 0, 0)
#define STAGE(kb, buf) { \
    char* xb = lds + (buf) * 16384; \
    char* wb = xb + 8192; \
    GLL(Xg + (size_t)r0 * E_ + (kb) + g0, xb + c0 * 16); \
    GLL(Xg + (size_t)r1 * E_ + (kb) + g1, xb + c1 * 16); \
    GLL(Wg + (size_t)r0 * E_ + (kb) + g0, wb + c0 * 16); \
    GLL(Wg + (size_t)r1 * E_ + (kb) + g1, wb + c1 * 16); }

    f32x4 acc[2][2];
#pragma unroll
    for (int nj = 0; nj < 2; ++nj) {
        int n0 = tn + wn * 32 + nj * 16 + ((lane >> 4) << 2);
        float4 b4 = *(const float4*)(bias + n0);
#pragma unroll
        for (int mi = 0; mi < 2; ++mi)
            acc[nj][mi] = f32x4{b4.x, b4.y, b4.z, b4.w};
    }

#define COMPSTEP(buf) { \
    const char* Xc = lds + (buf) * 16384; \
    const char* Wc = Xc + 8192; \
    __builtin_amdgcn_s_setprio(1); \
    _Pragma("unroll") \
    for (int kk = 0; kk < 2; ++kk) { \
        bf16x8 a0 = ld_frag(Wc, wn * 32 + (lane & 15), kk, lane); \
        bf16x8 a1 = ld_frag(Wc, wn * 32 + 16 + (lane & 15), kk, lane); \
        bf16x8 b0 = ld_frag(Xc, wm * 32 + (lane & 15), kk, lane); \
        bf16x8 b1 = ld_frag(Xc, wm * 32 + 16 + (lane & 15), kk, lane); \
        acc[0][0] = __builtin_amdgcn_mfma_f32_16x16x32_bf16(a0, b0, acc[0][0], 0, 0, 0); \
        acc[0][1] = __builtin_amdgcn_mfma_f32_16x16x32_bf16(a0, b1, acc[0][1], 0, 0, 0); \
        acc[1][0] = __builtin_amdgcn_mfma_f32_16x16x32_bf16(a1, b0, acc[1][0], 0, 0, 0); \
        acc[1][1] = __builtin_amdgcn_mfma_f32_16x16x32_bf16(a1, b1, acc[1][1], 0, 0, 0); \
    } \
    __builtin_amdgcn_s_setprio(0); }

    // prologue: tiles 0,1 in flight
    STAGE(0, 0);
    STAGE(64, 1);

    int cur = 0, nxt = 2;
    for (int t = 0; t < 10; ++t) {
        asm volatile("s_waitcnt vmcnt(4)" ::: "memory");   // my tile-t loads done (4 newer)
        __builtin_amdgcn_s_barrier();                      // raw: no implicit drain
        __builtin_amdgcn_sched_barrier(0);
        STAGE((t + 2) * 64, nxt);                          // stage t+2 (after barrier: safe reuse)
        COMPSTEP(cur);
        cur = cur == 2 ? 0 : cur + 1;
        nxt = nxt == 2 ? 0 : nxt + 1;
    }
    // tail: t=10 (tile 11 still in flight), t=11
    asm volatile("s_waitcnt vmcnt(4)" ::: "memory");
    __builtin_amdgcn_s_barrier();
    __builtin_amdgcn_sched_barrier(0);
    COMPSTEP(cur);
    cur = cur == 2 ? 0 : cur + 1;
    asm volatile("s_waitcnt vmcnt(0)" ::: "memory");
    __builtin_amdgcn_s_barrier();
    __builtin_amdgcn_sched_barrier(0);
    COMPSTEP(cur);

#pragma unroll
    for (int nj = 0; nj < 2; ++nj)
#pragma unroll
        for (int mi = 0; mi < 2; ++mi) {
            int n0 = tn + wn * 32 + nj * 16 + ((lane >> 4) << 2);
            int m  = tm + wm * 32 + mi * 16 + (lane & 15);
            u16x4 pk;
            pk[0] = f2bf(acc[nj][mi][0]); pk[1] = f2bf(acc[nj][mi][1]);
            pk[2] = f2bf(acc[nj][mi][2]); pk[3] = f2bf(acc[nj][mi][3]);
            *(u16x4*)(P + (size_t)m * E_ + n0) = pk;
        }
#undef GLL
#undef STAGE
#undef COMPSTEP
}

// ---------------- scores: per (b,h): out[i,j] = qs_i . kp_j + lin_b, fp32 out ----------------
// (R8/R9 structure: XCD-chunked swizzle; LDS-staged K; store-after-barrier overlap)
__global__ __launch_bounds__(256) void scores_kernel(
    const unsigned short* __restrict__ qs, const unsigned short* __restrict__ kp,
    const float* __restrict__ lin_b, float* __restrict__ out)
{
    __shared__ char lds[32768];   // Kb0, Kb1: 16KB each (128 rows x 64 bf16)

    int lid = blockIdx.x;
    int swz = (lid & 7) * 96 + (lid >> 3);   // 768 % 8 == 0, bijective
    int z   = swz >> 5;                      // 32 blocks per head
    int rem = swz & 31;
    int iy  = rem >> 2, jx = rem & 3;
    int b = z / H_, h = z - b * H_;

    int tid = threadIdx.x, lane = tid & 63, wid = tid >> 6;
    int wj = wid >> 1, wi = wid & 1;
    int ti = iy * 128, tj = jx * 256;

    const unsigned short* Qg = qs + (size_t)(b * S_) * E_ + h * 64;
    const unsigned short* Kg = kp + (size_t)(b * S_) * E_ + h * 64;

#define STAGEK(jbase, buf) { \
    char* lb = lds + (buf) * 16384; \
    _Pragma("unroll") \
    for (int pass = 0; pass < 4; ++pass) { \
        int c = pass * 256 + tid; \
        int row = c >> 3, cbg = (c & 7) ^ (row & 7); \
        __builtin_amdgcn_global_load_lds( \
            (const __attribute__((address_space(1))) void*)(Kg + (size_t)((jbase) + row) * E_ + cbg * 8), \
            (__attribute__((address_space(3))) void*)(lb + c * 16), 16, 0, 0); \
    } }

    bf16x8 qf[2][4];
    int qrow = ti + wi * 64 + (lane & 15);
#pragma unroll
    for (int ni = 0; ni < 4; ++ni)
#pragma unroll
        for (int kk = 0; kk < 2; ++kk)
            qf[kk][ni] = *(const bf16x8*)(Qg + (size_t)(qrow + ni * 16) * E_ + kk * 32 + ((lane >> 4) * 8));

    float lb0 = lin_b[0];
    float* O = out + ((size_t)z << 20);

    STAGEK(tj, 0);
    __syncthreads();                       // Kb0 ready
    STAGEK(tj + 128, 1);                   // prefetch second subtile (in flight)

    f32x4 acc[4][4];

    // ---- sub 0: compute ----
#pragma unroll
    for (int mj = 0; mj < 4; ++mj)
#pragma unroll
        for (int ni = 0; ni < 4; ++ni) acc[mj][ni] = f32x4{lb0, lb0, lb0, lb0};
#pragma unroll
    for (int kk = 0; kk < 2; ++kk) {
        bf16x8 a[4];
#pragma unroll
        for (int mj = 0; mj < 4; ++mj) a[mj] = ld_frag(lds, wj * 64 + mj * 16 + (lane & 15), kk, lane);
#pragma unroll
        for (int mj = 0; mj < 4; ++mj)
#pragma unroll
            for (int ni = 0; ni < 4; ++ni)
                acc[mj][ni] = __builtin_amdgcn_mfma_f32_16x16x32_bf16(a[mj], qf[kk][ni], acc[mj][ni], 0, 0, 0);
    }

    __syncthreads();                       // Kb1 staged; no stores outstanding yet

    // ---- sub 0: store (flies under sub1 compute) ----
#pragma unroll
    for (int mj = 0; mj < 4; ++mj)
#pragma unroll
        for (int ni = 0; ni < 4; ++ni) {
            int i  = ti + wi * 64 + ni * 16 + (lane & 15);
            int j0 = tj + wj * 64 + mj * 16 + ((lane >> 4) << 2);
            *(f32x4*)(O + (size_t)i * S_ + j0) = acc[mj][ni];
        }

    // ---- sub 1: compute ----
#pragma unroll
    for (int mj = 0; mj < 4; ++mj)
#pragma unroll
        for (int ni = 0; ni < 4; ++ni) acc[mj][ni] = f32x4{lb0, lb0, lb0, lb0};
#pragma unroll
    for (int kk = 0; kk < 2; ++kk) {
        bf16x8 a[4];
#pragma unroll
        for (int mj = 0; mj < 4; ++mj) a[mj] = ld_frag(lds + 16384, wj * 64 + mj * 16 + (lane & 15), kk, lane);
#pragma unroll
        for (int mj = 0; mj < 4; ++mj)
#pragma unroll
            for (int ni = 0; ni < 4; ++ni)
                acc[mj][ni] = __builtin_amdgcn_mfma_f32_16x16x32_bf16(a[mj], qf[kk][ni], acc[mj][ni], 0, 0, 0);
    }

    // ---- sub 1: store ----
#pragma unroll
    for (int mj = 0; mj < 4; ++mj)
#pragma unroll
        for (int ni = 0; ni < 4; ++ni) {
            int i  = ti + wi * 64 + ni * 16 + (lane & 15);
            int j0 = tj + 128 + wj * 64 + mj * 16 + ((lane >> 4) << 2);
            *(f32x4*)(O + (size_t)i * S_ + j0) = acc[mj][ni];
        }
#undef STAGEK
}

extern "C" void kernel_launch(void* const* d_in, const int* in_sizes, int n_in,
                              void* d_out, int out_size, void* d_ws, size_t ws_size,
                              hipStream_t stream)
{
    const float* k_in  = (const float*)d_in[0];
    const float* q_in  = (const float*)d_in[1];
    const float* Wq_w  = (const float*)d_in[2];
    const float* Wq_b  = (const float*)d_in[3];
    const float* Wk_w  = (const float*)d_in[4];
    const float* Wk_b  = (const float*)d_in[5];
    const float* lin_w = (const float*)d_in[6];
    const float* lin_b = (const float*)d_in[7];
    float* out = (float*)d_out;

    char* ws = (char*)d_ws;
    unsigned short* Wqbf = (unsigned short*)(ws + 0);
    unsigned short* Wkbf = (unsigned short*)(ws + 1179648);
    float*          bqs  = (float*)        (ws + 2359296);
    unsigned short* qbf  = (unsigned short*)(ws + 2362368);
    unsigned short* kbf  = (unsigned short*)(ws + 5508096);
    unsigned short* qsb  = (unsigned short*)(ws + 8653824);
    unsigned short* kpb  = (unsigned short*)(ws + 11799552);

    // 1) prep+cast (one 1D launch): Wq scaled->bf16, Wk->bf16, bqs, q->bf16, k->bf16
    prep_cast_kernel<<<dim3(4224), dim3(256), 0, stream>>>(q_in, k_in, Wq_w, Wk_w, Wq_b, lin_w,
                                                           Wqbf, Wkbf, qbf, kbf, bqs);
    // 2) projections: counted-vmcnt ring-3 pipeline + T5 setprio around MFMA
    proj_kernel<<<dim3(768), dim3(256), 0, stream>>>(qbf, kbf, Wqbf, Wkbf, bqs, Wk_b, qsb, kpb);
    // 3) scores (R9/R8 structure, unchanged)
    scores_kernel<<<dim3(768), dim3(256), 0, stream>>>(qsb, kpb, lin_b, out);
}